// Round 1
// baseline (87.272 us; speedup 1.0000x reference)
//
#include <hip/hip_runtime.h>

#define NB 16
#define NT 512
#define ND 384
#define MEL 2048
#define PACE 1.0f

// Kernel 1: one block per batch. Scan reps, build frame->token map, write dec_lens.
__global__ __launch_bounds__(NT) void fp_build_map(const int* __restrict__ durations,
                                                   int* __restrict__ idxmap,
                                                   float* __restrict__ dec_out) {
    const int b = blockIdx.x;
    const int t = threadIdx.x;
    __shared__ int s[NT];

    // init idxmap rows for this batch to -1 (frames past dec_len stay -1 -> zero output)
    for (int l = t; l < MEL; l += NT) idxmap[b * MEL + l] = -1;

    const int d = durations[b * NT + t];
    const int rep = (int)floorf((float)d / PACE + 0.5f);
    s[t] = rep;
    __syncthreads();

    // Hillis-Steele inclusive scan over 512 elements
    for (int off = 1; off < NT; off <<= 1) {
        int tmp = (t >= off) ? s[t - off] : 0;
        __syncthreads();
        s[t] += tmp;
        __syncthreads();
    }

    const int end = s[t];
    const int start = end - rep;
    for (int l = start; l < end && l < MEL; ++l) {
        idxmap[b * MEL + l] = t;
    }

    if (t == NT - 1) {
        int total = s[NT - 1];
        if (total > MEL) total = MEL;
        dec_out[b] = (float)total;
    }
}

// Kernel 2: float4 gather. One float4 per thread iteration; 96 float4 per row.
__global__ __launch_bounds__(256) void fp_gather(const float4* __restrict__ enc4,
                                                 const int* __restrict__ idxmap,
                                                 float4* __restrict__ out4) {
    const int V = ND / 4;                       // 96 float4 per row
    const int total = NB * MEL * V;             // 3,145,728
    const int stride = gridDim.x * blockDim.x;
    for (int f = blockIdx.x * blockDim.x + threadIdx.x; f < total; f += stride) {
        const int row = f / V;                  // b*MEL + l
        const int v = f - row * V;
        const int t = idxmap[row];
        float4 r = make_float4(0.f, 0.f, 0.f, 0.f);
        if (t >= 0) {
            const int b = row / MEL;
            r = enc4[(b * NT + t) * V + v];
        }
        out4[f] = r;
    }
}

extern "C" void kernel_launch(void* const* d_in, const int* in_sizes, int n_in,
                              void* d_out, int out_size, void* d_ws, size_t ws_size,
                              hipStream_t stream) {
    const int* durations = (const int*)d_in[0];
    const float* enc_out = (const float*)d_in[1];
    // d_in[2] is mel_max_len (=2048), compiled in as MEL

    float* out = (float*)d_out;
    float* dec_out = out + (size_t)NB * MEL * ND;   // dec_lens tail, as float
    int* idxmap = (int*)d_ws;                       // NB*MEL ints = 128 KiB

    fp_build_map<<<NB, NT, 0, stream>>>(durations, idxmap, dec_out);

    const int threads = 256;
    const int blocks = 2048;
    fp_gather<<<blocks, threads, 0, stream>>>((const float4*)enc_out, idxmap,
                                              (float4*)out);
}